// Round 1
// baseline (779.807 us; speedup 1.0000x reference)
//
#include <hip/hip_runtime.h>
#include <math.h>

// GCN 2-layer forward for MI355X.
// Inputs: x [N,512] f32, edge_index [2,E] int32, W1 [512,16], b1[16], W2[16,2], b2[2]
// Output: log_softmax over 2 classes, [N,2] f32.

#define DF 512
#define H1F 16

// ---- prep: degree (row-endpoint counts + self-loop) --------------------
__global__ void k_init_deg(float* __restrict__ deg, int n) {
    int i = blockIdx.x * blockDim.x + threadIdx.x;
    if (i < n) deg[i] = 1.0f;  // self-loop contribution
}

__global__ void k_deg_atomic(const int* __restrict__ rowi, float* __restrict__ deg, int E) {
    int e = blockIdx.x * blockDim.x + threadIdx.x;
    if (e < E) atomicAdd(&deg[rowi[e]], 1.0f);
}

__global__ void k_isqrt(const float* __restrict__ deg, float* __restrict__ isq, int n) {
    int i = blockIdx.x * blockDim.x + threadIdx.x;
    if (i < n) {
        float d = deg[i];
        isq[i] = d > 0.0f ? rsqrtf(d) : 0.0f;
    }
}

// ---- layer 1 GEMM: h1 = x @ W1; fused self-loop init of agg1 ------------
// Block: 256 threads = 16 rows x 16 cols; W1 staged transposed in LDS.
__global__ __launch_bounds__(256) void k_gemm1(const float* __restrict__ x,
                                               const float* __restrict__ W1,
                                               float* __restrict__ h1,
                                               const float* __restrict__ isq,
                                               float* __restrict__ agg1, int n) {
    __shared__ float wsT[16][516];  // transposed W1, padded: bank=(4c+k)%32
    int t = threadIdx.x;
    const float4* w4 = (const float4*)W1;  // [512][16] row-major, 2048 float4
    for (int i = t; i < 2048; i += 256) {
        float4 v = w4[i];
        int k = i >> 2;
        int c0 = (i & 3) << 2;
        wsT[c0 + 0][k] = v.x;
        wsT[c0 + 1][k] = v.y;
        wsT[c0 + 2][k] = v.z;
        wsT[c0 + 3][k] = v.w;
    }
    __syncthreads();
    int r = t >> 4, c = t & 15;
    long row = (long)blockIdx.x * 16 + r;
    if (row >= n) return;
    const float4* xr = (const float4*)(x + (size_t)row * DF);
    float acc = 0.0f;
#pragma unroll 4
    for (int kq = 0; kq < DF / 4; ++kq) {
        float4 xv = xr[kq];                               // 16 lanes/row share -> coalesced
        float4 wv = *(const float4*)&wsT[c][kq << 2];     // ds_read_b128
        acc = fmaf(xv.x, wv.x, acc);
        acc = fmaf(xv.y, wv.y, acc);
        acc = fmaf(xv.z, wv.z, acc);
        acc = fmaf(xv.w, wv.w, acc);
    }
    h1[row * H1F + c] = acc;
    float s = isq[row];
    agg1[row * H1F + c] = s * s * acc;  // self-loop term of segment_sum
}

// ---- layer 1 edge scatter: agg1[row] += norm * h1[col] ------------------
__global__ void k_scatter1(const int* __restrict__ rowi, const int* __restrict__ coli,
                           const float* __restrict__ isq, const float* __restrict__ h1,
                           float* __restrict__ agg1, int E) {
    int t = blockIdx.x * blockDim.x + threadIdx.x;
    int e = t >> 4, c = t & 15;
    if (e < E) {
        int r = rowi[e], cl = coli[e];
        float nrm = isq[r] * isq[cl];
        atomicAdd(&agg1[(size_t)r * H1F + c], nrm * h1[(size_t)cl * H1F + c]);
    }
}

// ---- layer 2 per-node: relu(agg1+b1) @ W2; self-loop init of agg2 -------
__global__ void k_layer2_node(const float* __restrict__ agg1, const float* __restrict__ b1,
                              const float* __restrict__ W2, const float* __restrict__ isq,
                              float* __restrict__ h2, float* __restrict__ agg2, int n) {
    int i = blockIdx.x * blockDim.x + threadIdx.x;
    if (i >= n) return;
    float o0 = 0.0f, o1 = 0.0f;
    const float4* a4 = (const float4*)(agg1 + (size_t)i * H1F);
#pragma unroll
    for (int q = 0; q < 4; ++q) {
        float4 v = a4[q];
        float vv[4] = {v.x, v.y, v.z, v.w};
#pragma unroll
        for (int j = 0; j < 4; ++j) {
            int c = q * 4 + j;
            float val = vv[j] + b1[c];
            val = val > 0.0f ? val : 0.0f;  // relu
            o0 = fmaf(val, W2[c * 2 + 0], o0);
            o1 = fmaf(val, W2[c * 2 + 1], o1);
        }
    }
    h2[(size_t)i * 2 + 0] = o0;
    h2[(size_t)i * 2 + 1] = o1;
    float s = isq[i] * isq[i];
    agg2[(size_t)i * 2 + 0] = s * o0;
    agg2[(size_t)i * 2 + 1] = s * o1;
}

// ---- layer 2 edge scatter ----------------------------------------------
__global__ void k_scatter2(const int* __restrict__ rowi, const int* __restrict__ coli,
                           const float* __restrict__ isq, const float* __restrict__ h2,
                           float* __restrict__ agg2, int E) {
    int e = blockIdx.x * blockDim.x + threadIdx.x;
    if (e < E) {
        int r = rowi[e], cl = coli[e];
        float nrm = isq[r] * isq[cl];
        atomicAdd(&agg2[(size_t)r * 2 + 0], nrm * h2[(size_t)cl * 2 + 0]);
        atomicAdd(&agg2[(size_t)r * 2 + 1], nrm * h2[(size_t)cl * 2 + 1]);
    }
}

// ---- finalize: out = log_softmax(agg2 + b2) in place --------------------
__global__ void k_finalize(float* __restrict__ out, const float* __restrict__ b2, int n) {
    int i = blockIdx.x * blockDim.x + threadIdx.x;
    if (i < n) {
        float a = out[(size_t)i * 2 + 0] + b2[0];
        float b = out[(size_t)i * 2 + 1] + b2[1];
        float m = fmaxf(a, b);
        float lse = m + logf(expf(a - m) + expf(b - m));
        out[(size_t)i * 2 + 0] = a - lse;
        out[(size_t)i * 2 + 1] = b - lse;
    }
}

extern "C" void kernel_launch(void* const* d_in, const int* in_sizes, int n_in,
                              void* d_out, int out_size, void* d_ws, size_t ws_size,
                              hipStream_t stream) {
    const float* x  = (const float*)d_in[0];
    const int*   ei = (const int*)d_in[1];
    const float* W1 = (const float*)d_in[2];
    const float* b1 = (const float*)d_in[3];
    const float* W2 = (const float*)d_in[4];
    const float* b2 = (const float*)d_in[5];

    int n = in_sizes[0] / DF;   // 100000
    int E = in_sizes[1] / 2;    // 3200000
    const int* rowi = ei;       // edge_index[0]
    const int* coli = ei + E;   // edge_index[1]

    float* ws   = (float*)d_ws;
    float* deg  = ws;                    // n
    float* isq  = ws + n;                // n
    float* h1   = ws + 2 * (size_t)n;    // n*16
    float* agg1 = ws + 18 * (size_t)n;   // n*16
    float* h2   = ws + 34 * (size_t)n;   // n*2
    float* out  = (float*)d_out;         // doubles as agg2 [n,2]

    const int B = 256;
    k_init_deg<<<(n + B - 1) / B, B, 0, stream>>>(deg, n);
    k_deg_atomic<<<(E + B - 1) / B, B, 0, stream>>>(rowi, deg, E);
    k_isqrt<<<(n + B - 1) / B, B, 0, stream>>>(deg, isq, n);
    k_gemm1<<<(n + 15) / 16, 256, 0, stream>>>(x, W1, h1, isq, agg1, n);
    {
        long tot = (long)E * H1F;
        k_scatter1<<<(int)((tot + B - 1) / B), B, 0, stream>>>(rowi, coli, isq, h1, agg1, E);
    }
    k_layer2_node<<<(n + B - 1) / B, B, 0, stream>>>(agg1, b1, W2, isq, h2, out, n);
    k_scatter2<<<(E + B - 1) / B, B, 0, stream>>>(rowi, coli, isq, h2, out, E);
    k_finalize<<<(n + B - 1) / B, B, 0, stream>>>(out, b2, n);
}

// Round 2
// 680.276 us; speedup vs baseline: 1.1463x; 1.1463x over previous
//
#include <hip/hip_runtime.h>
#include <math.h>

// GCN 2-layer forward, CSR-gather formulation (no float atomics).
// out = log_softmax( A @ relu( A @ (x@W1) + b1 ) @ W2 + b2 ),
// A = sym-normalized adjacency with self-loops, keyed on edge_index[0].

#define DF 512
#define H1F 16

// ---- zero degree counts -------------------------------------------------
__global__ void k_zero(unsigned int* __restrict__ deg, int n) {
    int i = blockIdx.x * blockDim.x + threadIdx.x;
    if (i < n) deg[i] = 0u;
}

// ---- count edges per source node ---------------------------------------
__global__ void k_deg_atomic(const int* __restrict__ rowi, unsigned int* __restrict__ deg, int E) {
    int e = blockIdx.x * blockDim.x + threadIdx.x;
    if (e < E) atomicAdd(&deg[rowi[e]], 1u);
}

// ---- isq = rsqrt(deg + 1)  (self-loop included) -------------------------
__global__ void k_isqrt(const unsigned int* __restrict__ deg, float* __restrict__ isq, int n) {
    int i = blockIdx.x * blockDim.x + threadIdx.x;
    if (i < n) isq[i] = rsqrtf((float)(deg[i] + 1u));
}

// ---- scan step 1: per-block sums of deg --------------------------------
__global__ __launch_bounds__(256) void k_bsum(const unsigned int* __restrict__ deg,
                                              unsigned int* __restrict__ bsum, int n) {
    __shared__ unsigned int s[256];
    int t = threadIdx.x;
    int i = blockIdx.x * 256 + t;
    s[t] = (i < n) ? deg[i] : 0u;
    __syncthreads();
    for (int off = 128; off > 0; off >>= 1) {
        if (t < off) s[t] += s[t + off];
        __syncthreads();
    }
    if (t == 0) bsum[blockIdx.x] = s[0];
}

// ---- scan step 2: exclusive scan of block sums (NB <= 512) --------------
__global__ __launch_bounds__(512) void k_scan_bsum(const unsigned int* __restrict__ bsum,
                                                   unsigned int* __restrict__ bpref, int NB) {
    __shared__ unsigned int s[512];
    int t = threadIdx.x;
    unsigned int v = (t < NB) ? bsum[t] : 0u;
    s[t] = v;
    __syncthreads();
    for (int off = 1; off < 512; off <<= 1) {
        unsigned int u = (t >= off) ? s[t - off] : 0u;
        __syncthreads();
        s[t] += u;
        __syncthreads();
    }
    if (t < NB) bpref[t] = s[t] - v;  // exclusive
}

// ---- scan step 3: local exclusive scan + block prefix → rowptr, cursor --
__global__ __launch_bounds__(256) void k_scan_local(const unsigned int* __restrict__ deg,
                                                    const unsigned int* __restrict__ bpref,
                                                    unsigned int* __restrict__ rowptr,
                                                    unsigned int* __restrict__ cursor, int n) {
    __shared__ unsigned int s[256];
    int t = threadIdx.x;
    int i = blockIdx.x * 256 + t;
    unsigned int d = (i < n) ? deg[i] : 0u;
    s[t] = d;
    __syncthreads();
    for (int off = 1; off < 256; off <<= 1) {
        unsigned int u = (t >= off) ? s[t - off] : 0u;
        __syncthreads();
        s[t] += u;
        __syncthreads();
    }
    if (i < n) {
        unsigned int start = bpref[blockIdx.x] + s[t] - d;
        rowptr[i] = start;
        cursor[i] = start;
    }
}

// ---- fill CSR columns via atomic cursor ---------------------------------
__global__ void k_fill(const int* __restrict__ rowi, const int* __restrict__ coli,
                       unsigned int* __restrict__ cursor, int* __restrict__ csr, int E) {
    int e = blockIdx.x * blockDim.x + threadIdx.x;
    if (e < E) {
        unsigned int pos = atomicAdd(&cursor[rowi[e]], 1u);
        csr[pos] = coli[e];
    }
}

// ---- layer 1 GEMM: h1 = x @ W1 ------------------------------------------
__global__ __launch_bounds__(256) void k_gemm1(const float* __restrict__ x,
                                               const float* __restrict__ W1,
                                               float* __restrict__ h1, int n) {
    __shared__ float wsT[16][516];  // W1 transposed, padded
    int t = threadIdx.x;
    const float4* w4 = (const float4*)W1;  // [512][16] row-major, 2048 float4
    for (int i = t; i < 2048; i += 256) {
        float4 v = w4[i];
        int k = i >> 2;
        int c0 = (i & 3) << 2;
        wsT[c0 + 0][k] = v.x;
        wsT[c0 + 1][k] = v.y;
        wsT[c0 + 2][k] = v.z;
        wsT[c0 + 3][k] = v.w;
    }
    __syncthreads();
    int r = t >> 4, c = t & 15;
    long row = (long)blockIdx.x * 16 + r;
    if (row >= n) return;
    const float4* xr = (const float4*)(x + (size_t)row * DF);
    float acc = 0.0f;
#pragma unroll 4
    for (int kq = 0; kq < DF / 4; ++kq) {
        float4 xv = xr[kq];
        float4 wv = *(const float4*)&wsT[c][kq << 2];
        acc = fmaf(xv.x, wv.x, acc);
        acc = fmaf(xv.y, wv.y, acc);
        acc = fmaf(xv.z, wv.z, acc);
        acc = fmaf(xv.w, wv.w, acc);
    }
    h1[row * H1F + c] = acc;
}

// ---- gather layer 1: r1 = relu(A @ h1 + b1), 4 lanes/row ----------------
__global__ __launch_bounds__(256) void k_gather1(const float* __restrict__ h1,
                                                 const unsigned int* __restrict__ rowptr,
                                                 const unsigned int* __restrict__ deg,
                                                 const int* __restrict__ csr,
                                                 const float* __restrict__ isq,
                                                 const float* __restrict__ b1,
                                                 float* __restrict__ r1, int n) {
    int tid = blockIdx.x * 256 + threadIdx.x;
    int r = tid >> 2, c = tid & 3;
    if (r >= n) return;
    float s = isq[r];
    float4 acc = *(const float4*)(h1 + (size_t)r * H1F + c * 4);
    float ss = s * s;  // self-loop norm
    acc.x *= ss; acc.y *= ss; acc.z *= ss; acc.w *= ss;
    unsigned int start = rowptr[r], cnt = deg[r];
    for (unsigned int k = 0; k < cnt; ++k) {
        int col = csr[start + k];
        float w = s * isq[col];
        float4 v = *(const float4*)(h1 + (size_t)col * H1F + c * 4);
        acc.x = fmaf(w, v.x, acc.x);
        acc.y = fmaf(w, v.y, acc.y);
        acc.z = fmaf(w, v.z, acc.z);
        acc.w = fmaf(w, v.w, acc.w);
    }
    float4 bb = ((const float4*)b1)[c];
    float4 o;
    o.x = fmaxf(acc.x + bb.x, 0.0f);
    o.y = fmaxf(acc.y + bb.y, 0.0f);
    o.z = fmaxf(acc.z + bb.z, 0.0f);
    o.w = fmaxf(acc.w + bb.w, 0.0f);
    *(float4*)(r1 + (size_t)r * H1F + c * 4) = o;
}

// ---- gather layer 2 + @W2 + b2 + log_softmax ----------------------------
__global__ __launch_bounds__(256) void k_gather2(const float* __restrict__ r1,
                                                 const unsigned int* __restrict__ rowptr,
                                                 const unsigned int* __restrict__ deg,
                                                 const int* __restrict__ csr,
                                                 const float* __restrict__ isq,
                                                 const float* __restrict__ W2,
                                                 const float* __restrict__ b2,
                                                 float* __restrict__ out, int n) {
    int tid = blockIdx.x * 256 + threadIdx.x;
    int r = tid >> 2, c = tid & 3;
    if (r >= n) return;
    float s = isq[r];
    float4 acc = *(const float4*)(r1 + (size_t)r * H1F + c * 4);
    float ss = s * s;
    acc.x *= ss; acc.y *= ss; acc.z *= ss; acc.w *= ss;
    unsigned int start = rowptr[r], cnt = deg[r];
    for (unsigned int k = 0; k < cnt; ++k) {
        int col = csr[start + k];
        float w = s * isq[col];
        float4 v = *(const float4*)(r1 + (size_t)col * H1F + c * 4);
        acc.x = fmaf(w, v.x, acc.x);
        acc.y = fmaf(w, v.y, acc.y);
        acc.z = fmaf(w, v.z, acc.z);
        acc.w = fmaf(w, v.w, acc.w);
    }
    // per-lane partial of g2 @ W2 (lane handles feats 4c..4c+3)
    int f0 = c * 4;
    float o0 = 0.0f, o1 = 0.0f;
    o0 = fmaf(acc.x, W2[(f0 + 0) * 2 + 0], o0); o1 = fmaf(acc.x, W2[(f0 + 0) * 2 + 1], o1);
    o0 = fmaf(acc.y, W2[(f0 + 1) * 2 + 0], o0); o1 = fmaf(acc.y, W2[(f0 + 1) * 2 + 1], o1);
    o0 = fmaf(acc.z, W2[(f0 + 2) * 2 + 0], o0); o1 = fmaf(acc.z, W2[(f0 + 2) * 2 + 1], o1);
    o0 = fmaf(acc.w, W2[(f0 + 3) * 2 + 0], o0); o1 = fmaf(acc.w, W2[(f0 + 3) * 2 + 1], o1);
    // reduce across the 4 lanes of this row
    o0 += __shfl_xor(o0, 1); o0 += __shfl_xor(o0, 2);
    o1 += __shfl_xor(o1, 1); o1 += __shfl_xor(o1, 2);
    if (c == 0) {
        float a = o0 + b2[0];
        float b = o1 + b2[1];
        float m = fmaxf(a, b);
        float lse = m + logf(expf(a - m) + expf(b - m));
        out[(size_t)r * 2 + 0] = a - lse;
        out[(size_t)r * 2 + 1] = b - lse;
    }
}

extern "C" void kernel_launch(void* const* d_in, const int* in_sizes, int n_in,
                              void* d_out, int out_size, void* d_ws, size_t ws_size,
                              hipStream_t stream) {
    const float* x  = (const float*)d_in[0];
    const int*   ei = (const int*)d_in[1];
    const float* W1 = (const float*)d_in[2];
    const float* b1 = (const float*)d_in[3];
    const float* W2 = (const float*)d_in[4];
    const float* b2 = (const float*)d_in[5];

    int n = in_sizes[0] / DF;   // 100000
    int E = in_sizes[1] / 2;    // 3200000
    const int* rowi = ei;       // edge_index[0] (output side)
    const int* coli = ei + E;   // edge_index[1] (gather side)

    const int B = 256;
    int NB = (n + B - 1) / B;   // 391 (<=512 required by scan)

    char* base = (char*)d_ws;
    unsigned int* deg    = (unsigned int*)base;                 base += (size_t)n * 4;
    float*        isq    = (float*)base;                        base += (size_t)n * 4;
    unsigned int* rowptr = (unsigned int*)base;                 base += (size_t)n * 4;
    unsigned int* cursor = (unsigned int*)base;                 base += (size_t)n * 4;
    unsigned int* bsum   = (unsigned int*)base;                 base += 512 * 4;
    unsigned int* bpref  = (unsigned int*)base;                 base += 512 * 4;
    float*        h1     = (float*)base;                        base += (size_t)n * H1F * 4;
    float*        r1     = (float*)base;                        base += (size_t)n * H1F * 4;
    int*          csr    = (int*)base;                          base += (size_t)E * 4;
    float*        out    = (float*)d_out;

    k_zero<<<NB, B, 0, stream>>>(deg, n);
    k_deg_atomic<<<(E + B - 1) / B, B, 0, stream>>>(rowi, deg, E);
    k_isqrt<<<NB, B, 0, stream>>>(deg, isq, n);
    k_bsum<<<NB, B, 0, stream>>>(deg, bsum, n);
    k_scan_bsum<<<1, 512, 0, stream>>>(bsum, bpref, NB);
    k_scan_local<<<NB, B, 0, stream>>>(deg, bpref, rowptr, cursor, n);
    k_fill<<<(E + B - 1) / B, B, 0, stream>>>(rowi, coli, cursor, csr, E);
    k_gemm1<<<(n + 15) / 16, 256, 0, stream>>>(x, W1, h1, n);
    {
        int work = n * 4;  // 4 lanes per row
        k_gather1<<<(work + B - 1) / B, B, 0, stream>>>(h1, rowptr, deg, csr, isq, b1, r1, n);
        k_gather2<<<(work + B - 1) / B, B, 0, stream>>>(r1, rowptr, deg, csr, isq, W2, b2, out, n);
    }
}